// Round 1
// baseline (606.541 us; speedup 1.0000x reference)
//
#include <hip/hip_runtime.h>

typedef __bf16 bf16x8 __attribute__((ext_vector_type(8)));
typedef float floatx4 __attribute__((ext_vector_type(4)));

#define AS1(p) ((const __attribute__((address_space(1))) unsigned int*)(p))
#define AS3(p) ((__attribute__((address_space(3))) unsigned int*)(p))

__device__ __forceinline__ void async_cp16(const void* g, void* l) {
  __builtin_amdgcn_global_load_lds(AS1(g), AS3(l), 16, 0, 0);
}

// ---------------------------------------------------------------------------
// Generic bf16 GEMM:  C[row][col] = scale * (sum_k A[row,k]*B[col,k] + bias)
// A: [M][K] k-contiguous (lda), B: [N][K] k-contiguous (ldb).
// grid = (N/128, M/128, batch). Optional fp32 residual add, fp32 or bf16 out.
// ---------------------------------------------------------------------------
template <bool OUT_F32>
__global__ __launch_bounds__(256, 2) void gemm_bt(
    const __bf16* __restrict__ A, const __bf16* __restrict__ B,
    void* __restrict__ Cv, const float* __restrict__ bias,
    const float* __restrict__ residual, int lda, int ldb, int ldc, long sA,
    long sB, long sC, long sR, int K, int bias_mode, float scale) {
  __shared__ alignas(16) __bf16 As[128 * 32];
  __shared__ alignas(16) __bf16 Bs[128 * 32];

  const int t = threadIdx.x;
  const int bz = blockIdx.z;
  const int m0 = blockIdx.y * 128;
  const int n0 = blockIdx.x * 128;

  const __bf16* Ab = A + (size_t)bz * sA;
  const __bf16* Bb = B + (size_t)bz * sB;

  // staging: 512 chunks of 16B per tile; thread covers chunk t and t+256
  const int sr = t >> 2;  // row 0..63
  const int sc = t & 3;   // 16B chunk within 64B row
  const __bf16* gA0 = Ab + (size_t)(m0 + sr) * lda + sc * 8;
  const __bf16* gA1 = gA0 + (size_t)64 * lda;
  const __bf16* gB0 = Bb + (size_t)(n0 + sr) * ldb + sc * 8;
  const __bf16* gB1 = gB0 + (size_t)64 * ldb;
  __bf16* lA0 = &As[t * 8];
  __bf16* lA1 = &As[(t + 256) * 8];
  __bf16* lB0 = &Bs[t * 8];
  __bf16* lB1 = &Bs[(t + 256) * 8];

  const int lane = t & 63;
  const int wv = t >> 6;
  const int wm = (wv & 1) * 64;
  const int wn = (wv >> 1) * 64;
  const int l15 = lane & 15;
  const int kg = lane >> 4;

  int aoff[4], boff[4];
#pragma unroll
  for (int i = 0; i < 4; ++i) aoff[i] = (wm + i * 16 + l15) * 32 + kg * 8;
#pragma unroll
  for (int j = 0; j < 4; ++j) boff[j] = (wn + j * 16 + l15) * 32 + kg * 8;

  floatx4 acc[4][4] = {};

  const int KT = K >> 5;
  for (int kt = 0; kt < KT; ++kt) {
    const size_t ko = (size_t)kt * 32;
    async_cp16(gA0 + ko, lA0);
    async_cp16(gA1 + ko, lA1);
    async_cp16(gB0 + ko, lB0);
    async_cp16(gB1 + ko, lB1);
    __syncthreads();
    bf16x8 af[4], bfr[4];
#pragma unroll
    for (int i = 0; i < 4; ++i) af[i] = *(const bf16x8*)&As[aoff[i]];
#pragma unroll
    for (int j = 0; j < 4; ++j) bfr[j] = *(const bf16x8*)&Bs[boff[j]];
#pragma unroll
    for (int i = 0; i < 4; ++i)
#pragma unroll
      for (int j = 0; j < 4; ++j)
        acc[i][j] = __builtin_amdgcn_mfma_f32_16x16x32_bf16(af[i], bfr[j],
                                                            acc[i][j], 0, 0, 0);
    __syncthreads();
  }

  // epilogue: C/D mapping col=lane&15, row=(lane>>4)*4+reg
  const int r0 = m0 + wm + (kg << 2);
  const int c0 = n0 + wn + l15;
#pragma unroll
  for (int i = 0; i < 4; ++i) {
#pragma unroll
    for (int r = 0; r < 4; ++r) {
      const int row = r0 + i * 16 + r;
      float brow = 0.f;
      if (bias_mode == 1) brow = bias[row];
#pragma unroll
      for (int j = 0; j < 4; ++j) {
        const int col = c0 + j * 16;
        float v = acc[i][j][r];
        if (bias_mode == 1)
          v += brow;
        else if (bias_mode == 2)
          v += bias[col];
        v *= scale;
        const size_t off = (size_t)row * ldc + col;
        if (OUT_F32) {
          float* Cf = (float*)Cv + (size_t)bz * sC;
          if (residual) v += residual[(size_t)bz * sR + off];
          Cf[off] = v;
        } else {
          __bf16* Cb = (__bf16*)Cv + (size_t)bz * sC;
          Cb[off] = (__bf16)v;
        }
      }
    }
  }
}

// ---------------------------------------------------------------------------
// GroupNorm: x[4][512][4096] fp32 -> Ht[4][4096][512] bf16 (transposed)
// one block per (batch, group); 16 channels x 4096 spatial per group
// ---------------------------------------------------------------------------
__global__ __launch_bounds__(256) void gn_kernel(const float* __restrict__ x,
                                                 const float* __restrict__ gamma,
                                                 const float* __restrict__ beta,
                                                 __bf16* __restrict__ Ht) {
  const int bg = blockIdx.x;
  const int bb = bg >> 5, g = bg & 31;
  const size_t xbase = ((size_t)bb * 512 + g * 16) * 4096;
  const int t = threadIdx.x;

  float s = 0.f, ss = 0.f;
  for (int idx = t; idx < 65536; idx += 256) {
    float v = x[xbase + idx];
    s += v;
    ss += v * v;
  }
#pragma unroll
  for (int off = 32; off; off >>= 1) {
    s += __shfl_down(s, off);
    ss += __shfl_down(ss, off);
  }
  __shared__ float red[8];
  if ((t & 63) == 0) {
    red[t >> 6] = s;
    red[4 + (t >> 6)] = ss;
  }
  __syncthreads();
  s = red[0] + red[1] + red[2] + red[3];
  ss = red[4] + red[5] + red[6] + red[7];
  const float mean = s * (1.f / 65536.f);
  const float var = ss * (1.f / 65536.f) - mean * mean;
  const float rstd = rsqrtf(var + 1e-5f);

  const int cl = t & 15;
  const int c = g * 16 + cl;
  const float ga = gamma[c] * rstd;
  const float be = beta[c] - mean * ga;
  __bf16* Hb = Ht + (size_t)bb * 4096 * 512 + c;
  const float* xc = x + xbase + (size_t)cl * 4096;
  for (int idx = t; idx < 65536; idx += 256) {
    const int nn = idx >> 4;
    Hb[(size_t)nn * 512] = (__bf16)(xc[nn] * ga + be);
  }
}

// ---------------------------------------------------------------------------
// In-place row softmax on S[16384][4096] bf16
// ---------------------------------------------------------------------------
__global__ __launch_bounds__(256) void softmax_kernel(__bf16* __restrict__ S) {
  __bf16* row = S + (size_t)blockIdx.x * 4096;
  const int t = threadIdx.x;
  bf16x8 v0 = ((const bf16x8*)row)[t];
  bf16x8 v1 = ((const bf16x8*)row)[t + 256];
  float f[16];
#pragma unroll
  for (int j = 0; j < 8; ++j) {
    f[j] = (float)v0[j];
    f[8 + j] = (float)v1[j];
  }
  float m = -1e30f;
#pragma unroll
  for (int k = 0; k < 16; ++k) m = fmaxf(m, f[k]);
#pragma unroll
  for (int off = 32; off; off >>= 1) m = fmaxf(m, __shfl_xor(m, off));
  __shared__ float red[8];
  if ((t & 63) == 0) red[t >> 6] = m;
  __syncthreads();
  m = fmaxf(fmaxf(red[0], red[1]), fmaxf(red[2], red[3]));

  float sum = 0.f;
#pragma unroll
  for (int k = 0; k < 16; ++k) {
    f[k] = __expf(f[k] - m);
    sum += f[k];
  }
#pragma unroll
  for (int off = 32; off; off >>= 1) sum += __shfl_xor(sum, off);
  if ((t & 63) == 0) red[4 + (t >> 6)] = sum;
  __syncthreads();
  sum = red[4] + red[5] + red[6] + red[7];
  const float inv = 1.0f / sum;

  bf16x8 o0, o1;
#pragma unroll
  for (int j = 0; j < 8; ++j) {
    o0[j] = (__bf16)(f[j] * inv);
    o1[j] = (__bf16)(f[8 + j] * inv);
  }
  ((bf16x8*)row)[t] = o0;
  ((bf16x8*)row)[t + 256] = o1;
}

__global__ void cvt_kernel(const float* __restrict__ w, __bf16* __restrict__ o,
                           int n) {
  int i = blockIdx.x * blockDim.x + threadIdx.x;
  if (i < n) o[i] = (__bf16)w[i];
}

// ---------------------------------------------------------------------------
extern "C" void kernel_launch(void* const* d_in, const int* in_sizes, int n_in,
                              void* d_out, int out_size, void* d_ws,
                              size_t ws_size, hipStream_t stream) {
  const float* x = (const float*)d_in[0];
  const float* gamma = (const float*)d_in[1];
  const float* beta = (const float*)d_in[2];
  const float* wq = (const float*)d_in[3];
  const float* bq = (const float*)d_in[4];
  const float* wk = (const float*)d_in[5];
  const float* bk = (const float*)d_in[6];
  const float* wv = (const float*)d_in[7];
  const float* bv = (const float*)d_in[8];
  const float* wo = (const float*)d_in[9];
  const float* bo = (const float*)d_in[10];

  // workspace layout (bf16 elements)
  __bf16* ws = (__bf16*)d_ws;
  __bf16* wqb = ws;                 // 512*512
  __bf16* wkb = wqb + 262144;
  __bf16* wvb = wkb + 262144;
  __bf16* wob = wvb + 262144;
  __bf16* Ht = wob + 262144;        // [4][4096][512]
  __bf16* Qt = Ht + 8388608;        // [4][4096][512]
  __bf16* Kt = Qt + 8388608;        // [4][4096][512]
  __bf16* Vm = Kt + 8388608;        // [4][512][4096]
  __bf16* Ot = Vm + 8388608;        // [4][4096][512]
  __bf16* S = Ot + 8388608;         // [4][4096][4096]
  const size_t need = (size_t)(4 * 262144 + 5 * 8388608 + 67108864) * 2;
  if (ws_size < need) return;  // workspace too small; bail cleanly

  cvt_kernel<<<1024, 256, 0, stream>>>(wq, wqb, 262144);
  cvt_kernel<<<1024, 256, 0, stream>>>(wk, wkb, 262144);
  cvt_kernel<<<1024, 256, 0, stream>>>(wv, wvb, 262144);
  cvt_kernel<<<1024, 256, 0, stream>>>(wo, wob, 262144);

  gn_kernel<<<128, 256, 0, stream>>>(x, gamma, beta, Ht);

  const long sH = 2097152;   // per-batch 4096*512
  const long sS = 16777216;  // per-batch 4096*4096
  const float qscale = 0.04419417382415922f;  // 512^-0.5

  // Qt[n][d] = qscale*(Ht[n,:]·wq[d,:] + bq[d])
  gemm_bt<false><<<dim3(4, 32, 4), 256, 0, stream>>>(
      Ht, wqb, Qt, bq, nullptr, 512, 512, 512, sH, 0, sH, 0, 512, 2, qscale);
  // Kt[m][d]
  gemm_bt<false><<<dim3(4, 32, 4), 256, 0, stream>>>(
      Ht, wkb, Kt, bk, nullptr, 512, 512, 512, sH, 0, sH, 0, 512, 2, 1.0f);
  // V[c][m] = wv[c,:]·Ht[m,:] + bv[c]
  gemm_bt<false><<<dim3(32, 4, 4), 256, 0, stream>>>(
      wvb, Ht, Vm, bv, nullptr, 512, 512, 4096, 0, sH, sH, 0, 512, 1, 1.0f);
  // S[n][m] = Qt[n,:]·Kt[m,:]
  gemm_bt<false><<<dim3(32, 32, 4), 256, 0, stream>>>(
      Qt, Kt, S, nullptr, nullptr, 512, 512, 4096, sH, sH, sS, 0, 512, 0, 1.0f);
  // softmax rows (in place)
  softmax_kernel<<<16384, 256, 0, stream>>>(S);
  // Ot[n][c] = P[n,:]·V[c,:]
  gemm_bt<false><<<dim3(4, 32, 4), 256, 0, stream>>>(
      S, Vm, Ot, nullptr, nullptr, 4096, 4096, 512, sS, sH, sH, 0, 4096, 0,
      1.0f);
  // y[d][n] = x[d][n] + wo[d,:]·Ot[n,:] + bo[d]   (fp32 out)
  gemm_bt<true><<<dim3(32, 4, 4), 256, 0, stream>>>(
      wob, Ot, d_out, bo, x, 512, 512, 4096, 0, sH, sH, sH, 512, 1, 1.0f);
}

// Round 2
// 471.777 us; speedup vs baseline: 1.2857x; 1.2857x over previous
//
#include <hip/hip_runtime.h>

typedef __bf16 bf16x8 __attribute__((ext_vector_type(8)));
typedef __bf16 bf16x4 __attribute__((ext_vector_type(4)));
typedef float floatx4 __attribute__((ext_vector_type(4)));

#define AS1(p) ((const __attribute__((address_space(1))) unsigned int*)(p))
#define AS3(p) ((__attribute__((address_space(3))) unsigned int*)(p))

__device__ __forceinline__ void async_cp16(const void* g, void* l) {
  __builtin_amdgcn_global_load_lds(AS1(g), AS3(l), 16, 0, 0);
}

// ---------------------------------------------------------------------------
// Generic bf16 GEMM:  C[row][col] = scale * (sum_k A[row,k]*B[col,k] + bias)
// A: [M][K] k-contiguous (lda), B: [N][K] k-contiguous (ldb).
// grid = (N/128, M/128, batch). Optional fp32 residual add, fp32 or bf16 out.
// ---------------------------------------------------------------------------
template <bool OUT_F32>
__global__ __launch_bounds__(256, 2) void gemm_bt(
    const __bf16* __restrict__ A, const __bf16* __restrict__ B,
    void* __restrict__ Cv, const float* __restrict__ bias,
    const float* __restrict__ residual, int lda, int ldb, int ldc, long sA,
    long sB, long sC, long sR, int K, int bias_mode, float scale) {
  __shared__ alignas(16) __bf16 As[128 * 32];
  __shared__ alignas(16) __bf16 Bs[128 * 32];

  const int t = threadIdx.x;
  const int bz = blockIdx.z;
  const int m0 = blockIdx.y * 128;
  const int n0 = blockIdx.x * 128;

  const __bf16* Ab = A + (size_t)bz * sA;
  const __bf16* Bb = B + (size_t)bz * sB;

  const int sr = t >> 2;  // row 0..63
  const int sc = t & 3;   // 16B chunk within 64B row
  const __bf16* gA0 = Ab + (size_t)(m0 + sr) * lda + sc * 8;
  const __bf16* gA1 = gA0 + (size_t)64 * lda;
  const __bf16* gB0 = Bb + (size_t)(n0 + sr) * ldb + sc * 8;
  const __bf16* gB1 = gB0 + (size_t)64 * ldb;
  __bf16* lA0 = &As[t * 8];
  __bf16* lA1 = &As[(t + 256) * 8];
  __bf16* lB0 = &Bs[t * 8];
  __bf16* lB1 = &Bs[(t + 256) * 8];

  const int lane = t & 63;
  const int wv = t >> 6;
  const int wm = (wv & 1) * 64;
  const int wn = (wv >> 1) * 64;
  const int l15 = lane & 15;
  const int kg = lane >> 4;

  int aoff[4], boff[4];
#pragma unroll
  for (int i = 0; i < 4; ++i) aoff[i] = (wm + i * 16 + l15) * 32 + kg * 8;
#pragma unroll
  for (int j = 0; j < 4; ++j) boff[j] = (wn + j * 16 + l15) * 32 + kg * 8;

  floatx4 acc[4][4] = {};

  const int KT = K >> 5;
  for (int kt = 0; kt < KT; ++kt) {
    const size_t ko = (size_t)kt * 32;
    async_cp16(gA0 + ko, lA0);
    async_cp16(gA1 + ko, lA1);
    async_cp16(gB0 + ko, lB0);
    async_cp16(gB1 + ko, lB1);
    __syncthreads();
    bf16x8 af[4], bfr[4];
#pragma unroll
    for (int i = 0; i < 4; ++i) af[i] = *(const bf16x8*)&As[aoff[i]];
#pragma unroll
    for (int j = 0; j < 4; ++j) bfr[j] = *(const bf16x8*)&Bs[boff[j]];
#pragma unroll
    for (int i = 0; i < 4; ++i)
#pragma unroll
      for (int j = 0; j < 4; ++j)
        acc[i][j] = __builtin_amdgcn_mfma_f32_16x16x32_bf16(af[i], bfr[j],
                                                            acc[i][j], 0, 0, 0);
    __syncthreads();
  }

  // epilogue: C/D mapping col=lane&15, row=(lane>>4)*4+reg
  const int r0 = m0 + wm + (kg << 2);
  const int c0 = n0 + wn + l15;
#pragma unroll
  for (int i = 0; i < 4; ++i) {
#pragma unroll
    for (int r = 0; r < 4; ++r) {
      const int row = r0 + i * 16 + r;
      float brow = 0.f;
      if (bias_mode == 1) brow = bias[row];
#pragma unroll
      for (int j = 0; j < 4; ++j) {
        const int col = c0 + j * 16;
        float v = acc[i][j][r];
        if (bias_mode == 1)
          v += brow;
        else if (bias_mode == 2)
          v += bias[col];
        v *= scale;
        const size_t off = (size_t)row * ldc + col;
        if (OUT_F32) {
          float* Cf = (float*)Cv + (size_t)bz * sC;
          if (residual) v += residual[(size_t)bz * sR + off];
          Cf[off] = v;
        } else {
          __bf16* Cb = (__bf16*)Cv + (size_t)bz * sC;
          Cb[off] = (__bf16)v;
        }
      }
    }
  }
}

// ---------------------------------------------------------------------------
// GroupNorm pass 1: partial sums. grid 1024 = (b,g) 128 x 8 segments.
// part[1024][2] = {sum, sumsq} of 8192-elem segment.
// ---------------------------------------------------------------------------
__global__ __launch_bounds__(256) void gn_stats(const float* __restrict__ x,
                                                float* __restrict__ part) {
  const int t = threadIdx.x;
  const size_t base = (size_t)blockIdx.x * 8192;
  const floatx4* xp = (const floatx4*)(x + base);
  float s = 0.f, ss = 0.f;
#pragma unroll
  for (int i = 0; i < 8; ++i) {
    floatx4 v = xp[t + i * 256];
#pragma unroll
    for (int k = 0; k < 4; ++k) {
      s += v[k];
      ss += v[k] * v[k];
    }
  }
#pragma unroll
  for (int off = 32; off; off >>= 1) {
    s += __shfl_down(s, off);
    ss += __shfl_down(ss, off);
  }
  __shared__ float red[8];
  if ((t & 63) == 0) {
    red[t >> 6] = s;
    red[4 + (t >> 6)] = ss;
  }
  __syncthreads();
  if (t == 0) {
    part[blockIdx.x * 2] = red[0] + red[1] + red[2] + red[3];
    part[blockIdx.x * 2 + 1] = red[4] + red[5] + red[6] + red[7];
  }
}

// ---------------------------------------------------------------------------
// GroupNorm pass 2: per-(b,c) scale/shift. 2048 threads.
// ---------------------------------------------------------------------------
__global__ __launch_bounds__(256) void gn_finalize(
    const float* __restrict__ part, const float* __restrict__ gamma,
    const float* __restrict__ beta, float* __restrict__ sc,
    float* __restrict__ sh) {
  const int tid = blockIdx.x * 256 + threadIdx.x;  // b*512 + c
  const int b = tid >> 9, c = tid & 511;
  const int bg = b * 32 + (c >> 4);
  float s = 0.f, ss = 0.f;
#pragma unroll
  for (int k = 0; k < 8; ++k) {
    s += part[(bg * 8 + k) * 2];
    ss += part[(bg * 8 + k) * 2 + 1];
  }
  const float mean = s * (1.f / 65536.f);
  const float var = ss * (1.f / 65536.f) - mean * mean;
  const float rstd = rsqrtf(var + 1e-5f);
  const float g = gamma[c] * rstd;
  sc[tid] = g;
  sh[tid] = beta[c] - mean * g;
}

// ---------------------------------------------------------------------------
// GroupNorm pass 3: normalize + transpose. x[b][c][n] f32 -> Ht[b][n][c] bf16
// grid (64, 8, 4): 64x64 tile per block, LDS transpose.
// ---------------------------------------------------------------------------
__global__ __launch_bounds__(256) void gn_xform(const float* __restrict__ x,
                                                const float* __restrict__ sc,
                                                const float* __restrict__ sh,
                                                __bf16* __restrict__ Ht) {
  __shared__ float tile[64][65];
  const int t = threadIdx.x;
  const int b = blockIdx.z;
  const int c0 = blockIdx.y * 64;
  const int n0 = blockIdx.x * 64;

#pragma unroll
  for (int i = 0; i < 4; ++i) {
    const int slot = i * 256 + t;
    const int c = slot >> 4;            // 0..63
    const int nc = (slot & 15) * 4;     // 0..60
    const int ch = c0 + c;
    const floatx4 v =
        *(const floatx4*)&x[((size_t)b * 512 + ch) * 4096 + n0 + nc];
    const float scl = sc[b * 512 + ch];
    const float shf = sh[b * 512 + ch];
#pragma unroll
    for (int k = 0; k < 4; ++k) tile[c][nc + k] = v[k] * scl + shf;
  }
  __syncthreads();
#pragma unroll
  for (int i = 0; i < 4; ++i) {
    const int slot = i * 256 + t;
    const int n = slot >> 4;            // 0..63
    const int cc = (slot & 15) * 4;     // 0..60
    bf16x4 o;
#pragma unroll
    for (int k = 0; k < 4; ++k) o[k] = (__bf16)tile[cc + k][n];
    *(bf16x4*)&Ht[((size_t)b * 4096 + n0 + n) * 512 + c0 + cc] = o;
  }
}

// ---------------------------------------------------------------------------
// In-place row softmax on S[16384][4096] bf16
// ---------------------------------------------------------------------------
__global__ __launch_bounds__(256) void softmax_kernel(__bf16* __restrict__ S) {
  __bf16* row = S + (size_t)blockIdx.x * 4096;
  const int t = threadIdx.x;
  bf16x8 v0 = ((const bf16x8*)row)[t];
  bf16x8 v1 = ((const bf16x8*)row)[t + 256];
  float f[16];
#pragma unroll
  for (int j = 0; j < 8; ++j) {
    f[j] = (float)v0[j];
    f[8 + j] = (float)v1[j];
  }
  float m = -1e30f;
#pragma unroll
  for (int k = 0; k < 16; ++k) m = fmaxf(m, f[k]);
#pragma unroll
  for (int off = 32; off; off >>= 1) m = fmaxf(m, __shfl_xor(m, off));
  __shared__ float red[8];
  if ((t & 63) == 0) red[t >> 6] = m;
  __syncthreads();
  m = fmaxf(fmaxf(red[0], red[1]), fmaxf(red[2], red[3]));

  float sum = 0.f;
#pragma unroll
  for (int k = 0; k < 16; ++k) {
    f[k] = __expf(f[k] - m);
    sum += f[k];
  }
#pragma unroll
  for (int off = 32; off; off >>= 1) sum += __shfl_xor(sum, off);
  if ((t & 63) == 0) red[4 + (t >> 6)] = sum;
  __syncthreads();
  sum = red[4] + red[5] + red[6] + red[7];
  const float inv = 1.0f / sum;

  bf16x8 o0, o1;
#pragma unroll
  for (int j = 0; j < 8; ++j) {
    o0[j] = (__bf16)(f[j] * inv);
    o1[j] = (__bf16)(f[8 + j] * inv);
  }
  ((bf16x8*)row)[t] = o0;
  ((bf16x8*)row)[t + 256] = o1;
}

// fused 4-weight f32->bf16 convert: grid 4096, 1024 blocks per weight
__global__ void cvt4_kernel(const float* w0, const float* w1, const float* w2,
                            const float* w3, __bf16* o0, __bf16* o1,
                            __bf16* o2, __bf16* o3) {
  const int wsel = blockIdx.x >> 10;
  const int i = (blockIdx.x & 1023) * 256 + threadIdx.x;
  const float* w = wsel == 0 ? w0 : wsel == 1 ? w1 : wsel == 2 ? w2 : w3;
  __bf16* o = wsel == 0 ? o0 : wsel == 1 ? o1 : wsel == 2 ? o2 : o3;
  o[i] = (__bf16)w[i];
}

// ---------------------------------------------------------------------------
extern "C" void kernel_launch(void* const* d_in, const int* in_sizes, int n_in,
                              void* d_out, int out_size, void* d_ws,
                              size_t ws_size, hipStream_t stream) {
  const float* x = (const float*)d_in[0];
  const float* gamma = (const float*)d_in[1];
  const float* beta = (const float*)d_in[2];
  const float* wq = (const float*)d_in[3];
  const float* bq = (const float*)d_in[4];
  const float* wk = (const float*)d_in[5];
  const float* bk = (const float*)d_in[6];
  const float* wv = (const float*)d_in[7];
  const float* bv = (const float*)d_in[8];
  const float* wo = (const float*)d_in[9];
  const float* bo = (const float*)d_in[10];

  // workspace layout (bf16 elements)
  __bf16* ws = (__bf16*)d_ws;
  __bf16* wqb = ws;                 // 512*512
  __bf16* wkb = wqb + 262144;
  __bf16* wvb = wkb + 262144;
  __bf16* wob = wvb + 262144;
  __bf16* Ht = wob + 262144;        // [4][4096][512]
  __bf16* Qt = Ht + 8388608;        // [4][4096][512]
  __bf16* Kt = Qt + 8388608;        // [4][4096][512]
  __bf16* Vm = Kt + 8388608;        // [4][512][4096]
  __bf16* Ot = Vm + 8388608;        // [4][4096][512]
  __bf16* S = Ot + 8388608;         // [4][4096][4096]
  const size_t need = (size_t)(4 * 262144 + 5 * 8388608 + 67108864) * 2;
  if (ws_size < need) return;

  // gn scratch lives in S region (S written later by QK^T gemm)
  float* part = (float*)S;          // [1024][2]
  float* scb = part + 2048;         // [4][512]
  float* shb = scb + 2048;          // [4][512]

  cvt4_kernel<<<4096, 256, 0, stream>>>(wq, wk, wv, wo, wqb, wkb, wvb, wob);

  gn_stats<<<1024, 256, 0, stream>>>(x, part);
  gn_finalize<<<8, 256, 0, stream>>>(part, gamma, beta, scb, shb);
  gn_xform<<<dim3(64, 8, 4), 256, 0, stream>>>(x, scb, shb, Ht);

  const long sH = 2097152;   // per-batch 4096*512
  const long sS = 16777216;  // per-batch 4096*4096
  const float qscale = 0.04419417382415922f;  // 512^-0.5

  // Qt[n][d] = qscale*(Ht[n,:]·wq[d,:] + bq[d])
  gemm_bt<false><<<dim3(4, 32, 4), 256, 0, stream>>>(
      Ht, wqb, Qt, bq, nullptr, 512, 512, 512, sH, 0, sH, 0, 512, 2, qscale);
  // Kt[m][d]
  gemm_bt<false><<<dim3(4, 32, 4), 256, 0, stream>>>(
      Ht, wkb, Kt, bk, nullptr, 512, 512, 512, sH, 0, sH, 0, 512, 2, 1.0f);
  // V[c][m] = wv[c,:]·Ht[m,:] + bv[c]
  gemm_bt<false><<<dim3(32, 4, 4), 256, 0, stream>>>(
      wvb, Ht, Vm, bv, nullptr, 512, 512, 4096, 0, sH, sH, 0, 512, 1, 1.0f);
  // S[n][m] = Qt[n,:]·Kt[m,:]
  gemm_bt<false><<<dim3(32, 32, 4), 256, 0, stream>>>(
      Qt, Kt, S, nullptr, nullptr, 512, 512, 4096, sH, sH, sS, 0, 512, 0, 1.0f);
  // softmax rows (in place)
  softmax_kernel<<<16384, 256, 0, stream>>>(S);
  // Ot[n][c] = P[n,:]·V[c,:]
  gemm_bt<false><<<dim3(4, 32, 4), 256, 0, stream>>>(
      S, Vm, Ot, nullptr, nullptr, 4096, 4096, 512, sS, sH, sH, 0, 4096, 0,
      1.0f);
  // y[d][n] = x[d][n] + wo[d,:]·Ot[n,:] + bo[d]   (fp32 out)
  gemm_bt<true><<<dim3(32, 4, 4), 256, 0, stream>>>(
      wob, Ot, d_out, bo, x, 512, 512, 4096, 0, sH, sH, sH, 512, 1, 1.0f);
}